// Round 2
// baseline (937.421 us; speedup 1.0000x reference)
//
#include <hip/hip_runtime.h>
#include <math.h>

#define IMG 112
#define CDIM 128
#define NTOK 49

// ---------------- K1: qkv[m][0:384] = x_shift[m][:] @ w_qkv + b_qkv ----------------
// tile 64(M) x 64(N), K=128 processed in two 64-chunks. A stored transposed in LDS.
__global__ __launch_bounds__(256) void qkv_gemm_kernel(
    const float* __restrict__ x, const float* __restrict__ w,
    const float* __restrict__ bqkv, float* __restrict__ qkv)
{
    __shared__ float At[64][68];   // At[c][r], c = k within chunk
    __shared__ float Bs[64][68];   // Bs[c][j]
    const int tid = threadIdx.x;
    const int m0 = blockIdx.x * 64;
    const int j0 = blockIdx.y * 64;
    const int tm = tid >> 4, tn = tid & 15;

    float acc[4][4];
#pragma unroll
    for (int i = 0; i < 4; i++)
#pragma unroll
        for (int j = 0; j < 4; j++) acc[i][j] = 0.0f;

    for (int kc = 0; kc < 2; kc++) {
        if (kc) __syncthreads();
        // A chunk: 64 rows x 64 k, transposed store
        for (int idx = tid; idx < 64 * 16; idx += 256) {
            int r = idx >> 4;
            int c4 = (idx & 15) << 2;
            int m = m0 + r;
            int b = m / (IMG * IMG);
            int rem = m - b * (IMG * IMG);
            int hh = rem / IMG;
            int ww_ = rem - hh * IMG;
            int hs = hh + 3; if (hs >= IMG) hs -= IMG;   // roll(-3) fold
            int ws = ww_ + 3; if (ws >= IMG) ws -= IMG;
            float4 v = *(const float4*)(x + ((size_t)((b * IMG + hs) * IMG + ws)) * CDIM + kc * 64 + c4);
            At[c4 + 0][r] = v.x;
            At[c4 + 1][r] = v.y;
            At[c4 + 2][r] = v.z;
            At[c4 + 3][r] = v.w;
        }
        // B chunk: 64 k x 64 j
        for (int idx = tid; idx < 64 * 16; idx += 256) {
            int c = idx >> 4;
            int j4 = (idx & 15) << 2;
            float4 v = *(const float4*)(w + (size_t)(kc * 64 + c) * 384 + j0 + j4);
            *(float4*)(&Bs[c][j4]) = v;
        }
        __syncthreads();
#pragma unroll 4
        for (int c = 0; c < 64; c++) {
            float4 a4 = *(const float4*)(&At[c][tm << 2]);
            float4 b4 = *(const float4*)(&Bs[c][tn << 2]);
            float av[4] = {a4.x, a4.y, a4.z, a4.w};
            float bv[4] = {b4.x, b4.y, b4.z, b4.w};
#pragma unroll
            for (int i = 0; i < 4; i++)
#pragma unroll
                for (int j = 0; j < 4; j++) acc[i][j] = fmaf(av[i], bv[j], acc[i][j]);
        }
    }
#pragma unroll
    for (int i = 0; i < 4; i++) {
        int m = m0 + (tm << 2) + i;
        int j = j0 + (tn << 2);
        float4 o;
        o.x = acc[i][0] + bqkv[j];
        o.y = acc[i][1] + bqkv[j + 1];
        o.z = acc[i][2] + bqkv[j + 2];
        o.w = acc[i][3] + bqkv[j + 3];
        *(float4*)(qkv + (size_t)m * 384 + j) = o;
    }
}

// ---------------- K2: per-window attention + fused proj ----------------
#define SOS 132   // out-tile stride (all 128 channels)
#define SQH 36    // per-head q/k/v stride
#define SSC 50    // score stride
#define OFF_OS 0
#define OFF_Q 6468
#define OFF_K 8232
#define OFF_V 9996
#define OFF_SC 11760
#define OFF_WP 6468          // aliases q/k/v region (free during proj)
#define SMEM_FLOATS 14210    // 56.8 KB

__global__ __launch_bounds__(256) void attn_kernel(
    const float* __restrict__ qkv, const float* __restrict__ wproj,
    const float* __restrict__ bproj, const float* __restrict__ lsig,
    const float* __restrict__ btab, float* __restrict__ out)
{
    __shared__ float sm[SMEM_FLOATS];
    const int tid = threadIdx.x;
    const int bx = blockIdx.x;
    const int b  = bx >> 8;
    const int wi = (bx >> 4) & 15;
    const int wj = bx & 15;
    const float scale = 0.17677669529663687f;  // 32^-0.5

    float* osb = sm + OFF_OS;
    float* qh  = sm + OFF_Q;
    float* kh  = sm + OFF_K;
    float* vh  = sm + OFF_V;
    float* scb = sm + OFF_SC;

    for (int h = 0; h < 4; h++) {
        // gather this head's q,k,v (q,k pre-scaled)
        for (int idx = tid; idx < NTOK * 8; idx += 256) {
            int n = idx >> 3;
            int d4 = (idx & 7) << 2;
            int ph = n / 7, pw = n - ph * 7;
            size_t gm = (size_t)((b * IMG + wi * 7 + ph) * IMG + wj * 7 + pw);
            const float* row = qkv + gm * 384 + h * 32 + d4;
            float4 q4 = *(const float4*)(row);
            float4 k4 = *(const float4*)(row + 128);
            float4 v4 = *(const float4*)(row + 256);
            q4.x *= scale; q4.y *= scale; q4.z *= scale; q4.w *= scale;
            k4.x *= scale; k4.y *= scale; k4.z *= scale; k4.w *= scale;
            *(float4*)(qh + n * SQH + d4) = q4;
            *(float4*)(kh + n * SQH + d4) = k4;
            *(float4*)(vh + n * SQH + d4) = v4;
        }
        __syncthreads();
        float coef = -0.5f * expf(-2.0f * lsig[h]);
        // scores: -0.5/sigma^2 * |q-k|^2 + bias + mask
        for (int idx = tid; idx < NTOK * NTOK; idx += 256) {
            int n = idx / 49;
            int m = idx - n * 49;
            const float* qp = qh + n * SQH;
            const float* kp = kh + m * SQH;
            float dist = 0.0f;
#pragma unroll
            for (int d4 = 0; d4 < 8; d4++) {
                float4 q4 = *(const float4*)(qp + (d4 << 2));
                float4 k4 = *(const float4*)(kp + (d4 << 2));
                float e0 = q4.x - k4.x, e1 = q4.y - k4.y;
                float e2 = q4.z - k4.z, e3 = q4.w - k4.w;
                dist = fmaf(e0, e0, dist); dist = fmaf(e1, e1, dist);
                dist = fmaf(e2, e2, dist); dist = fmaf(e3, e3, dist);
            }
            dist = fmaxf(dist, 1e-12f);
            int nh_ = n / 7, nw_ = n - nh_ * 7;
            int mh_ = m / 7, mw_ = m - mh_ * 7;
            int rpi = (nh_ - mh_ + 6) * 13 + (nw_ - mw_ + 6);
            float bias = btab[rpi * 4 + h];
            // region codes: rows [105,109) -> ph 0..3 = group 1; rows [109,112) -> ph 4..6 = group 2
            int cn = ((wi == 15) ? (nh_ < 4 ? 1 : 2) : 0) * 3 + ((wj == 15) ? (nw_ < 4 ? 1 : 2) : 0);
            int cm = ((wi == 15) ? (mh_ < 4 ? 1 : 2) : 0) * 3 + ((wj == 15) ? (mw_ < 4 ? 1 : 2) : 0);
            float maskv = (cn != cm) ? -100.0f : 0.0f;
            scb[n * SSC + m] = fmaf(coef, dist, bias + maskv);
        }
        __syncthreads();
        // softmax per row (49 rows)
        if (tid < NTOK) {
            float* rowp = scb + tid * SSC;
            float mx = -1e30f;
            for (int m = 0; m < NTOK; m++) mx = fmaxf(mx, rowp[m]);
            float s = 0.0f;
            for (int m = 0; m < NTOK; m++) { float e = expf(rowp[m] - mx); rowp[m] = e; s += e; }
            float inv = 1.0f / s;
            for (int m = 0; m < NTOK; m++) rowp[m] *= inv;
        }
        __syncthreads();
        // PV -> out tile columns of this head
        for (int idx = tid; idx < NTOK * 8; idx += 256) {
            int n = idx >> 3;
            int d4 = (idx & 7) << 2;
            const float* srow = scb + n * SSC;
            float4 a = {0.f, 0.f, 0.f, 0.f};
            for (int m = 0; m < NTOK; m++) {
                float p = srow[m];
                float4 v4 = *(const float4*)(vh + m * SQH + d4);
                a.x = fmaf(p, v4.x, a.x);
                a.y = fmaf(p, v4.y, a.y);
                a.z = fmaf(p, v4.z, a.z);
                a.w = fmaf(p, v4.w, a.w);
            }
            *(float4*)(osb + n * SOS + h * 32 + d4) = a;
        }
        __syncthreads();
    }

    // fused proj: out_tile(49x128) @ w_proj(128x128) + b_proj, w_proj staged 32-k at a time
    float4 pacc[7];
#pragma unroll
    for (int u = 0; u < 7; u++) {
        int idx = tid + (u << 8);
        if (idx < NTOK * 32) {
            int e4 = (idx & 31) << 2;
            pacc[u] = make_float4(bproj[e4], bproj[e4 + 1], bproj[e4 + 2], bproj[e4 + 3]);
        }
    }
    float* wp = sm + OFF_WP;
    for (int ch = 0; ch < 4; ch++) {
        __syncthreads();
        for (int idx = tid; idx < 1024; idx += 256)
            ((float4*)wp)[idx] = ((const float4*)(wproj + (size_t)(ch << 5) * 128))[idx];
        __syncthreads();
#pragma unroll
        for (int u = 0; u < 7; u++) {
            int idx = tid + (u << 8);
            if (idx < NTOK * 32) {
                int n = idx >> 5;
                int e4 = (idx & 31) << 2;
                const float* orow = osb + n * SOS + (ch << 5);
                const float* wrow = wp + e4;
                float4 a = pacc[u];
#pragma unroll 8
                for (int cc = 0; cc < 32; cc++) {
                    float o = orow[cc];
                    float4 w4 = *(const float4*)(wrow + cc * 128);
                    a.x = fmaf(o, w4.x, a.x);
                    a.y = fmaf(o, w4.y, a.y);
                    a.z = fmaf(o, w4.z, a.z);
                    a.w = fmaf(o, w4.w, a.w);
                }
                pacc[u] = a;
            }
        }
    }
    // store with inverse roll (+3,+3)
#pragma unroll
    for (int u = 0; u < 7; u++) {
        int idx = tid + (u << 8);
        if (idx < NTOK * 32) {
            int n = idx >> 5;
            int e4 = (idx & 31) << 2;
            int ph = n / 7, pw = n - ph * 7;
            int ho = wi * 7 + ph + 3; if (ho >= IMG) ho -= IMG;
            int wo = wj * 7 + pw + 3; if (wo >= IMG) wo -= IMG;
            *(float4*)(out + ((size_t)((b * IMG + ho) * IMG + wo)) * CDIM + e4) = pacc[u];
        }
    }
}

extern "C" void kernel_launch(void* const* d_in, const int* in_sizes, int n_in,
                              void* d_out, int out_size, void* d_ws, size_t ws_size,
                              hipStream_t stream)
{
    const float* x         = (const float*)d_in[0];
    const float* w_qkv     = (const float*)d_in[1];
    const float* b_qkv     = (const float*)d_in[2];
    const float* w_proj    = (const float*)d_in[3];
    const float* b_proj    = (const float*)d_in[4];
    const float* log_sigma = (const float*)d_in[5];
    const float* bias_tab  = (const float*)d_in[6];
    float* out = (float*)d_out;
    float* qkv = (float*)d_ws;   // 200704*384 floats = 308 MB

    dim3 g1(200704 / 64, 6);
    qkv_gemm_kernel<<<g1, 256, 0, stream>>>(x, w_qkv, b_qkv, qkv);
    attn_kernel<<<4096, 256, 0, stream>>>(qkv, w_proj, b_proj, log_sigma, bias_tab, out);
}